// Round 1
// baseline (19481.299 us; speedup 1.0000x reference)
//
#include <hip/hip_runtime.h>
#include <hip/hip_bf16.h>
#include <stdint.h>

// GRU B=64 T=512 I=512 H=1024, fp32 in/out.
// Strategy: bf16 hi/lo split 3-pass MFMA everywhere (error ~1e-5 rel, fp32-like).
//  - One big projection GEMM  [B*T,512] @ W'[3072,1536]^T  (K'=3K encodes 3 passes)
//  - 512 sequential steps, 2 kernels each: phase1 (z,r + s=r*h), phase2 (h~ + update)
// U'/W' pre-split into [hi,lo,hi] K-blocks; A side uses [hi,hi,lo] column mapping.

#define B_ 64
#define T_ 512
#define I_ 512
#define H_ 1024

typedef __attribute__((ext_vector_type(4))) float f32x4;
typedef __attribute__((ext_vector_type(8))) short s16x8;

__device__ __forceinline__ unsigned short f2bf(float f) {
  union { float f; uint32_t u; } v; v.f = f;
  uint32_t u = v.u;
  u += 0x7fffu + ((u >> 16) & 1u);   // RNE
  return (unsigned short)(u >> 16);
}
__device__ __forceinline__ float bf2f(unsigned short h) {
  union { uint32_t u; float f; } v; v.u = ((uint32_t)h) << 16;
  return v.f;
}

// src [N][K] fp32 -> dst [N][3K] bf16 as [hi | lo | hi] K-blocks. K = 1<<kshift.
__global__ void k_split(const float* __restrict__ src, uint16_t* __restrict__ dst,
                        int kshift, int total) {
  int K = 1 << kshift;
  for (int i = blockIdx.x * blockDim.x + threadIdx.x; i < total;
       i += gridDim.x * blockDim.x) {
    int n = i >> kshift, k = i & (K - 1);
    float f = src[i];
    unsigned short hi = f2bf(f);
    unsigned short lo = f2bf(f - bf2f(hi));
    size_t base = (size_t)n * (3 * K);
    dst[base + k] = hi;
    dst[base + K + k] = lo;
    dst[base + 2 * K + k] = hi;
  }
}

// h = h0 ; h2 = [hi(1024) | lo(1024)] per row
__global__ void k_init(const float* __restrict__ h0, float* __restrict__ h,
                       uint16_t* __restrict__ h2) {
  for (int i = blockIdx.x * blockDim.x + threadIdx.x; i < B_ * H_;
       i += gridDim.x * blockDim.x) {
    float f = h0[i];
    h[i] = f;
    int b = i >> 10, j = i & 1023;
    unsigned short hi = f2bf(f);
    h2[b * 2048 + j] = hi;
    h2[b * 2048 + 1024 + j] = f2bf(f - bf2f(hi));
  }
}

// Projection GEMM: rows n=(b,tt) of chunk, cols 0..3071 (z|r|h gates), K'=1536.
// A' col map: xcol = k'&511, flavor = hi if k'<1024 else lo (matches W' [hi|lo|hi]).
// Writes XP[tt][gate][b][j] fp32 (+bias).
__global__ __launch_bounds__(256) void k_proj(
    const float* __restrict__ x, const uint16_t* __restrict__ W2,
    const float* __restrict__ bz, const float* __restrict__ br,
    const float* __restrict__ bh,
    float* __restrict__ XP, int t0, int Tc, int MT) {
  __shared__ uint16_t As[128][72];   // +8 pad: stride 144B, 16B aligned, banks free
  __shared__ uint16_t Bs[128][72];
  int bid = blockIdx.x;
  int mt = bid % MT, nt = bid / MT;
  int tid = threadIdx.x;
  int w = tid >> 6, l = tid & 63;
  int wm = w >> 1, wn = w & 1;
  int lr = l & 15, lg = l >> 4;

  int gr[4], gc8[4];
  const float* asrc[4];
  const uint16_t* bsrc[4];
#pragma unroll
  for (int g = 0; g < 4; ++g) {
    int gran = tid + 256 * g;
    int r = gran >> 3, c8 = gran & 7;
    gr[g] = r; gc8[g] = c8;
    int n = mt * 128 + r;
    int b = n / Tc, tt = n % Tc;
    asrc[g] = x + ((size_t)b * T_ + (t0 + tt)) * I_;
    bsrc[g] = W2 + (size_t)(nt * 128 + r) * 1536;
  }

  f32x4 acc[4][4];
#pragma unroll
  for (int mi = 0; mi < 4; ++mi)
#pragma unroll
    for (int ni = 0; ni < 4; ++ni) {
      acc[mi][ni][0] = 0.f; acc[mi][ni][1] = 0.f;
      acc[mi][ni][2] = 0.f; acc[mi][ni][3] = 0.f;
    }

  float4 pa[8];
  uint4 pb[4];
  // prologue loads (iter 0)
#pragma unroll
  for (int g = 0; g < 4; ++g) {
    int kp = gc8[g] * 8;
    int xc = kp & 511;
    pa[2 * g] = *(const float4*)(asrc[g] + xc);
    pa[2 * g + 1] = *(const float4*)(asrc[g] + xc + 4);
    pb[g] = *(const uint4*)(bsrc[g] + kp);
  }

  for (int it = 0; it < 24; ++it) {
    __syncthreads();
    // commit staged regs -> LDS (convert A fp32 -> bf16 hi/lo flavor)
    {
      int k0 = it * 64;
#pragma unroll
      for (int g = 0; g < 4; ++g) {
        int kp = k0 + gc8[g] * 8;
        bool lofl = (kp >= 1024);
        const float* pf = (const float*)&pa[2 * g];
        s16x8 v;
#pragma unroll
        for (int j = 0; j < 8; ++j) {
          float f = pf[j];
          unsigned short hi = f2bf(f);
          v[j] = (short)(lofl ? f2bf(f - bf2f(hi)) : hi);
        }
        *(s16x8*)(&As[gr[g]][gc8[g] * 8]) = v;
        *(uint4*)(&Bs[gr[g]][gc8[g] * 8]) = pb[g];
      }
    }
    // prefetch next iter
    if (it + 1 < 24) {
      int k0 = (it + 1) * 64;
#pragma unroll
      for (int g = 0; g < 4; ++g) {
        int kp = k0 + gc8[g] * 8;
        int xc = kp & 511;
        pa[2 * g] = *(const float4*)(asrc[g] + xc);
        pa[2 * g + 1] = *(const float4*)(asrc[g] + xc + 4);
        pb[g] = *(const uint4*)(bsrc[g] + kp);
      }
    }
    __syncthreads();
#pragma unroll
    for (int kk = 0; kk < 64; kk += 32) {
      s16x8 af[4], bf[4];
#pragma unroll
      for (int mi = 0; mi < 4; ++mi)
        af[mi] = *(const s16x8*)(&As[wm * 64 + mi * 16 + lr][kk + lg * 8]);
#pragma unroll
      for (int ni = 0; ni < 4; ++ni)
        bf[ni] = *(const s16x8*)(&Bs[wn * 64 + ni * 16 + lr][kk + lg * 8]);
#pragma unroll
      for (int mi = 0; mi < 4; ++mi)
#pragma unroll
        for (int ni = 0; ni < 4; ++ni)
          acc[mi][ni] = __builtin_amdgcn_mfma_f32_16x16x32_bf16(
              af[mi], bf[ni], acc[mi][ni], 0, 0, 0);
    }
  }

  // epilogue: D row=(lg*4+v), col=lr (m89-verified layout)
  int g_ = (nt * 128) >> 10;
  const float* bias = (g_ == 0) ? bz : ((g_ == 1) ? br : bh);
#pragma unroll
  for (int ni = 0; ni < 4; ++ni) {
    int col = nt * 128 + wn * 64 + ni * 16 + lr;
    int jc = col & 1023;
    float bv = bias[jc];
#pragma unroll
    for (int mi = 0; mi < 4; ++mi) {
      int nrow = mt * 128 + wm * 64 + mi * 16 + lg * 4;
      int b = nrow / Tc, tt = nrow % Tc;
#pragma unroll
      for (int v = 0; v < 4; ++v) {
        XP[((size_t)((tt * 3 + g_) * 64 + b)) * 1024 + jc] = acc[mi][ni][v] + bv;
        if (++tt == Tc) { tt = 0; ++b; }
      }
    }
  }
}

// phase1: ZR = h' @ Uzr'^T  (M=64, N=2048, K'=3072), then z=sigmoid(.), r=sigmoid(.),
// s2 = split(r*h).  128 wgs x 512thr; 8 K-eighths per wg, LDS reduce.
__global__ __launch_bounds__(512) void k_phase1(
    const uint16_t* __restrict__ h2, const uint16_t* __restrict__ U2,
    const float* __restrict__ XP, int tt,
    const float* __restrict__ h, float* __restrict__ zbuf,
    uint16_t* __restrict__ s2) {
  __shared__ float red[8][64][16];
  int tid = threadIdx.x, w = tid >> 6, l = tid & 63;
  int lr = l & 15, lg = l >> 4;
  int bid = blockIdx.x;
  int strip = (bid & 7) * 16 + (bid >> 3);   // XCD-pin U' column strips
  int n0 = strip * 16;
  int kbase = w * 384;

  f32x4 acc[4];
#pragma unroll
  for (int mi = 0; mi < 4; ++mi) {
    acc[mi][0] = 0.f; acc[mi][1] = 0.f; acc[mi][2] = 0.f; acc[mi][3] = 0.f;
  }
  const uint16_t* brow = U2 + (size_t)(n0 + lr) * 3072;
#pragma unroll 4
  for (int ks = 0; ks < 12; ++ks) {
    int kp = kbase + ks * 32 + lg * 8;
    int ac = (kp < 1024) ? kp : kp - 1024;   // A' = [hi|hi|lo]
    s16x8 bfv = *(const s16x8*)(brow + kp);
#pragma unroll
    for (int mi = 0; mi < 4; ++mi) {
      s16x8 afv = *(const s16x8*)(h2 + (size_t)(lr + 16 * mi) * 2048 + ac);
      acc[mi] = __builtin_amdgcn_mfma_f32_16x16x32_bf16(afv, bfv, acc[mi], 0, 0, 0);
    }
  }
#pragma unroll
  for (int mi = 0; mi < 4; ++mi)
#pragma unroll
    for (int v = 0; v < 4; ++v)
      red[w][mi * 16 + lg * 4 + v][lr] = acc[mi][v];
  __syncthreads();
  for (int e = tid; e < 1024; e += 512) {
    int b = e >> 4, c = e & 15;
    float s = 0.f;
#pragma unroll
    for (int q = 0; q < 8; ++q) s += red[q][b][c];
    int n = n0 + c;
    if (n < 1024) {
      float pre = s + XP[((size_t)(tt * 3 + 0) * 64 + b) * 1024 + n];
      zbuf[b * 1024 + n] = 1.f / (1.f + __expf(-pre));
    } else {
      int j = n - 1024;
      float pre = s + XP[((size_t)(tt * 3 + 1) * 64 + b) * 1024 + j];
      float r = 1.f / (1.f + __expf(-pre));
      float sv = r * h[b * 1024 + j];
      unsigned short hi = f2bf(sv);
      s2[b * 2048 + j] = hi;
      s2[b * 2048 + 1024 + j] = f2bf(sv - bf2f(hi));
    }
  }
}

// phase2: HT = s' @ Uh'^T (M=64,N=1024,K'=3072); h_new=(1-z)h+z*tanh(xh+HT);
// writes h, h2, out[:,t,:] (+h_last at t==T-1).
__global__ __launch_bounds__(512) void k_phase2(
    const uint16_t* __restrict__ s2, const uint16_t* __restrict__ Uh2,
    const float* __restrict__ XP, int tt, int t,
    float* __restrict__ h, const float* __restrict__ zbuf,
    uint16_t* __restrict__ h2, float* __restrict__ out) {
  __shared__ float red[8][64][16];
  int tid = threadIdx.x, w = tid >> 6, l = tid & 63;
  int lr = l & 15, lg = l >> 4;
  int bid = blockIdx.x;
  int strip = (bid & 7) * 8 + (bid >> 3);   // 64 wgs
  int n0 = strip * 16;
  int kbase = w * 384;

  f32x4 acc[4];
#pragma unroll
  for (int mi = 0; mi < 4; ++mi) {
    acc[mi][0] = 0.f; acc[mi][1] = 0.f; acc[mi][2] = 0.f; acc[mi][3] = 0.f;
  }
  const uint16_t* brow = Uh2 + (size_t)(n0 + lr) * 3072;
#pragma unroll 4
  for (int ks = 0; ks < 12; ++ks) {
    int kp = kbase + ks * 32 + lg * 8;
    int ac = (kp < 1024) ? kp : kp - 1024;
    s16x8 bfv = *(const s16x8*)(brow + kp);
#pragma unroll
    for (int mi = 0; mi < 4; ++mi) {
      s16x8 afv = *(const s16x8*)(s2 + (size_t)(lr + 16 * mi) * 2048 + ac);
      acc[mi] = __builtin_amdgcn_mfma_f32_16x16x32_bf16(afv, bfv, acc[mi], 0, 0, 0);
    }
  }
#pragma unroll
  for (int mi = 0; mi < 4; ++mi)
#pragma unroll
    for (int v = 0; v < 4; ++v)
      red[w][mi * 16 + lg * 4 + v][lr] = acc[mi][v];
  __syncthreads();
  for (int e = tid; e < 1024; e += 512) {
    int b = e >> 4, c = e & 15;
    float s = 0.f;
#pragma unroll
    for (int q = 0; q < 8; ++q) s += red[q][b][c];
    int j = n0 + c;
    float pre = s + XP[((size_t)(tt * 3 + 2) * 64 + b) * 1024 + j];
    float ht = tanhf(pre);
    float z = zbuf[b * 1024 + j];
    float hv = h[b * 1024 + j];
    float hn = (1.f - z) * hv + z * ht;
    h[b * 1024 + j] = hn;
    unsigned short hi = f2bf(hn);
    h2[b * 2048 + j] = hi;
    h2[b * 2048 + 1024 + j] = f2bf(hn - bf2f(hi));
    out[((size_t)b * T_ + t) * 1024 + j] = hn;
    if (t == T_ - 1) out[(size_t)B_ * T_ * 1024 + b * 1024 + j] = hn;
  }
}

extern "C" void kernel_launch(void* const* d_in, const int* in_sizes, int n_in,
                              void* d_out, int out_size, void* d_ws, size_t ws_size,
                              hipStream_t stream) {
  const float* x  = (const float*)d_in[0];
  const float* h0 = (const float*)d_in[1];
  const float* Wz = (const float*)d_in[2];
  const float* bz = (const float*)d_in[3];
  const float* Uz = (const float*)d_in[4];
  const float* Wr = (const float*)d_in[5];
  const float* br = (const float*)d_in[6];
  const float* Ur = (const float*)d_in[7];
  const float* Wh = (const float*)d_in[8];
  const float* bh = (const float*)d_in[9];
  const float* Uh = (const float*)d_in[10];
  float* out = (float*)d_out;

  uint8_t* ws = (uint8_t*)d_ws;
  uint16_t* Uzr2 = (uint16_t*)(ws + 0);          // [2048][3072] bf16
  uint16_t* Uh2  = (uint16_t*)(ws + 12582912);   // [1024][3072]
  uint16_t* W2   = (uint16_t*)(ws + 18874368);   // [3072][1536]
  float*    hbuf = (float*)   (ws + 28311552);   // [64][1024]
  uint16_t* h2   = (uint16_t*)(ws + 28573696);   // [64][2048]
  uint16_t* s2   = (uint16_t*)(ws + 28835840);   // [64][2048]
  float*    zbuf = (float*)   (ws + 29097984);   // [64][1024]
  float*    XP   = (float*)   (ws + 29360128);   // [Tc][3][64][1024] fp32

  size_t avail = (ws_size > 29360128u) ? (ws_size - 29360128u) : 0u;
  long long tcl = (long long)(avail / 786432u);  // bytes per timestep of XP
  int Tc = (tcl > 512) ? 512 : (int)tcl;
  Tc &= ~1;                 // even so B*Tc % 128 == 0
  if (Tc < 2) Tc = 2;       // require ws >= ~31MB

  // weight splits (once per call; deterministic)
  k_split<<<512, 256, 0, stream>>>(Uz, Uzr2, 10, 1024 * 1024);
  k_split<<<512, 256, 0, stream>>>(Ur, Uzr2 + (size_t)1024 * 3072, 10, 1024 * 1024);
  k_split<<<512, 256, 0, stream>>>(Uh, Uh2, 10, 1024 * 1024);
  k_split<<<512, 256, 0, stream>>>(Wz, W2, 9, 1024 * 512);
  k_split<<<512, 256, 0, stream>>>(Wr, W2 + (size_t)1024 * 1536, 9, 1024 * 512);
  k_split<<<512, 256, 0, stream>>>(Wh, W2 + (size_t)2048 * 1536, 9, 1024 * 512);
  k_init<<<64, 256, 0, stream>>>(h0, hbuf, h2);

  for (int t0 = 0; t0 < T_; t0 += Tc) {
    int Tcc = (Tc < T_ - t0) ? Tc : (T_ - t0);
    int MT = (B_ * Tcc) / 128;
    k_proj<<<MT * 24, 256, 0, stream>>>(x, W2, bz, br, bh, XP, t0, Tcc, MT);
    for (int tt = 0; tt < Tcc; ++tt) {
      k_phase1<<<128, 512, 0, stream>>>(h2, Uzr2, XP, tt, hbuf, zbuf, s2);
      k_phase2<<<64, 512, 0, stream>>>(s2, Uh2, XP, tt, t0 + tt, hbuf, zbuf, h2, out);
    }
  }
}